// Round 1
// baseline (6621.884 us; speedup 1.0000x reference)
//
#include <hip/hip_runtime.h>
#include <stdint.h>

#define Cc   16
#define HIDD 128
#define Bn   8
#define Hh   256
#define Ww   256
#define HW   (Hh * Ww)         // 65536
#define NPIX (Bn * HW)         // 524288
#define NSTEPS 32

// ---------------- JAX threefry2x32 (20 rounds), host+device ----------------
__host__ __device__ inline void threefry2x32(uint32_t k1, uint32_t k2,
                                             uint32_t x0, uint32_t x1,
                                             uint32_t& o0, uint32_t& o1) {
  const uint32_t ks2 = k1 ^ k2 ^ 0x1BD11BDAu;
  uint32_t v0 = x0 + k1;
  uint32_t v1 = x1 + k2;
#define ROTL32(x, n) (((x) << (n)) | ((x) >> (32 - (n))))
#define R4(a, b, c, d)                                    \
  { v0 += v1; v1 = ROTL32(v1, a); v1 ^= v0;               \
    v0 += v1; v1 = ROTL32(v1, b); v1 ^= v0;               \
    v0 += v1; v1 = ROTL32(v1, c); v1 ^= v0;               \
    v0 += v1; v1 = ROTL32(v1, d); v1 ^= v0; }
  R4(13, 15, 26, 6)   v0 += k2;  v1 += ks2 + 1u;
  R4(17, 29, 16, 24)  v0 += ks2; v1 += k1 + 2u;
  R4(13, 15, 26, 6)   v0 += k1;  v1 += k2 + 3u;
  R4(17, 29, 16, 24)  v0 += k2;  v1 += ks2 + 4u;
  R4(13, 15, 26, 6)   v0 += ks2; v1 += k1 + 5u;
#undef R4
#undef ROTL32
  o0 = v0;
  o1 = v1;
}

// ---------------- NCHW -> NHWC state init ----------------
__global__ __launch_bounds__(256) void k_nchw_to_nhwc(const float* __restrict__ x,
                                                      float* __restrict__ st) {
  const int p = blockIdx.x * 256 + threadIdx.x;
  const int b = p >> 16;
  const int hw = p & 65535;
  const float* src = x + (size_t)b * (Cc * HW) + hw;
  float v[16];
#pragma unroll
  for (int c = 0; c < 16; c++) v[c] = src[(size_t)c * HW];
  float4* dst = (float4*)(st + (size_t)p * 16);
#pragma unroll
  for (int q = 0; q < 4; q++)
    dst[q] = make_float4(v[4 * q], v[4 * q + 1], v[4 * q + 2], v[4 * q + 3]);
}

// ---------------- One NCA step ----------------
__global__ __launch_bounds__(256) void k_step(const float* __restrict__ in,
                                              float* __restrict__ out,
                                              const float* __restrict__ wp0,
                                              const float* __restrict__ wp1,
                                              const float* __restrict__ wfc0,
                                              const float* __restrict__ bfc0,
                                              const float* __restrict__ wfc1,
                                              uint32_t key0, uint32_t key1) {
  // LDS-staged weights. w_fc0 transposed to [d][c] so the inner c-loop is
  // contiguous -> ds_read_b128 (row stride 48 floats = 192 B, 16B-aligned).
  __shared__ float s_w0T[HIDD * 48];
  __shared__ float s_w1[HIDD * 16];
  __shared__ float s_p0[9 * 16];
  __shared__ float s_p1[9 * 16];
  __shared__ float s_b[HIDD];

  const int tid = threadIdx.x;
  for (int i = tid; i < HIDD * 48; i += 256) {
    int c = i >> 7;       // 0..47
    int d = i & 127;      // 0..127
    s_w0T[d * 48 + c] = wfc0[i];
  }
  for (int i = tid; i < HIDD * 16; i += 256) s_w1[i] = wfc1[i];
  if (tid < 144) { s_p0[tid] = wp0[tid]; s_p1[tid] = wp1[tid]; }
  if (tid < 128) s_b[tid] = bfc0[tid];
  __syncthreads();

  const int b = blockIdx.x >> 8;
  const int h = blockIdx.x & 255;
  const int w = tid;
  // 'reflect' padding: -1 -> 1, H -> H-2
  const int rows[3] = { (h == 0) ? 1 : h - 1, h, (h == 255) ? 254 : h + 1 };
  const int cols[3] = { (w == 0) ? 1 : w - 1, w, (w == 255) ? 254 : w + 1 };

  float perc[48];
#pragma unroll
  for (int i = 16; i < 48; i++) perc[i] = 0.f;

#pragma unroll
  for (int ty = 0; ty < 3; ty++) {
#pragma unroll
    for (int tx = 0; tx < 3; tx++) {
      const int tap = ty * 3 + tx;
      const float4* pv =
          (const float4*)(in + (size_t)(((b << 8) + rows[ty]) * 256 + cols[tx]) * 16);
#pragma unroll
      for (int q = 0; q < 4; q++) {
        float4 v = pv[q];
        float vv[4] = { v.x, v.y, v.z, v.w };
#pragma unroll
        for (int j = 0; j < 4; j++) {
          const int c = 4 * q + j;
          perc[16 + c] = fmaf(s_p0[tap * 16 + c], vv[j], perc[16 + c]);
          perc[32 + c] = fmaf(s_p1[tap * 16 + c], vv[j], perc[32 + c]);
          if (tap == 4) perc[c] = vv[j];
        }
      }
    }
  }

  float dx[16];
#pragma unroll
  for (int c = 0; c < 16; c++) dx[c] = 0.f;

#pragma unroll 2
  for (int d = 0; d < HIDD; d++) {
    float hd = s_b[d];
    const float* wr = &s_w0T[d * 48];
#pragma unroll
    for (int c = 0; c < 48; c++) hd = fmaf(perc[c], wr[c], hd);
    hd = fmaxf(hd, 0.f);
    const float* w1r = &s_w1[d * 16];
#pragma unroll
    for (int c = 0; c < 16; c++) dx[c] = fmaf(hd, w1r[c], dx[c]);
  }

  // JAX partitionable threefry uniform: bits = out0 ^ out1 of
  // threefry(step_key, (hi=0, lo=linear_pixel_index))
  const uint32_t p = (uint32_t)((blockIdx.x << 8) + w);
  uint32_t o0, o1;
  threefry2x32(key0, key1, 0u, p, o0, o1);
  const uint32_t bits = o0 ^ o1;
  const float u = __uint_as_float((bits >> 9) | 0x3f800000u) - 1.0f;
  const float mask = (u <= 0.5f) ? 1.0f : 0.0f;

  float o[16];
#pragma unroll
  for (int c = 0; c < 16; c++)
    o[c] = (c < 3) ? perc[c] : fmaf(mask, dx[c], perc[c]);
  float4* dst = (float4*)(out + (size_t)p * 16);
#pragma unroll
  for (int q = 0; q < 4; q++)
    dst[q] = make_float4(o[4 * q], o[4 * q + 1], o[4 * q + 2], o[4 * q + 3]);
}

// ---------------- NHWC state -> (out slice, x_final NCHW) ----------------
__global__ __launch_bounds__(256) void k_nhwc_to_out(const float* __restrict__ st,
                                                     float* __restrict__ outp) {
  const int p = blockIdx.x * 256 + threadIdx.x;
  const int b = p >> 16;
  const int hw = p & 65535;
  const float4* src = (const float4*)(st + (size_t)p * 16);
  float v[16];
#pragma unroll
  for (int q = 0; q < 4; q++) {
    float4 t = src[q];
    v[4 * q] = t.x; v[4 * q + 1] = t.y; v[4 * q + 2] = t.z; v[4 * q + 3] = t.w;
  }
  float* xf = outp + NPIX;  // x_final region of d_out
#pragma unroll
  for (int c = 0; c < 16; c++) xf[(size_t)(b * 16 + c) * HW + hw] = v[c];
  outp[(size_t)b * HW + hw] = v[3];  // out = x_final[:, 3:4]
}

extern "C" void kernel_launch(void* const* d_in, const int* in_sizes, int n_in,
                              void* d_out, int out_size, void* d_ws, size_t ws_size,
                              hipStream_t stream) {
  const float* x    = (const float*)d_in[0];
  const float* wp0  = (const float*)d_in[1];
  const float* wp1  = (const float*)d_in[2];
  const float* wfc0 = (const float*)d_in[3];
  const float* bfc0 = (const float*)d_in[4];
  const float* wfc1 = (const float*)d_in[5];
  float* out = (float*)d_out;

  float* S0 = (float*)d_ws;      // 33.5 MB scratch state
  float* S1 = out + NPIX;        // x_final region doubles as scratch

  // Step keys: foldlike split of key(42): keys[s] = threefry((0,42),(0,s))
  uint32_t k0[NSTEPS], k1[NSTEPS];
  for (int s = 0; s < NSTEPS; s++)
    threefry2x32(0u, 42u, 0u, (uint32_t)s, k0[s], k1[s]);

  dim3 grid(Bn * Hh), block(256);
  hipLaunchKernelGGL(k_nchw_to_nhwc, grid, block, 0, stream, x, S0);
  float* cur = S0;
  float* nxt = S1;
  for (int s = 0; s < NSTEPS; s++) {
    hipLaunchKernelGGL(k_step, grid, block, 0, stream,
                       cur, nxt, wp0, wp1, wfc0, bfc0, wfc1, k0[s], k1[s]);
    float* t = cur; cur = nxt; nxt = t;
  }
  // 32 steps (even) -> final state back in S0
  hipLaunchKernelGGL(k_nhwc_to_out, grid, block, 0, stream, cur, out);
}

// Round 2
// 4314.038 us; speedup vs baseline: 1.5350x; 1.5350x over previous
//
#include <hip/hip_runtime.h>
#include <stdint.h>

#define Cc   16
#define HIDD 128
#define Bn   8
#define Hh   256
#define Ww   256
#define HW   (Hh * Ww)         // 65536
#define NPIX (Bn * HW)         // 524288
#define NSTEPS 32

// ---------------- JAX threefry2x32 (20 rounds), host+device ----------------
__host__ __device__ inline void threefry2x32(uint32_t k1, uint32_t k2,
                                             uint32_t x0, uint32_t x1,
                                             uint32_t& o0, uint32_t& o1) {
  const uint32_t ks2 = k1 ^ k2 ^ 0x1BD11BDAu;
  uint32_t v0 = x0 + k1;
  uint32_t v1 = x1 + k2;
#define ROTL32(x, n) (((x) << (n)) | ((x) >> (32 - (n))))
#define R4(a, b, c, d)                                    \
  { v0 += v1; v1 = ROTL32(v1, a); v1 ^= v0;               \
    v0 += v1; v1 = ROTL32(v1, b); v1 ^= v0;               \
    v0 += v1; v1 = ROTL32(v1, c); v1 ^= v0;               \
    v0 += v1; v1 = ROTL32(v1, d); v1 ^= v0; }
  R4(13, 15, 26, 6)   v0 += k2;  v1 += ks2 + 1u;
  R4(17, 29, 16, 24)  v0 += ks2; v1 += k1 + 2u;
  R4(13, 15, 26, 6)   v0 += k1;  v1 += k2 + 3u;
  R4(17, 29, 16, 24)  v0 += k2;  v1 += ks2 + 4u;
  R4(13, 15, 26, 6)   v0 += ks2; v1 += k1 + 5u;
#undef R4
#undef ROTL32
  o0 = v0;
  o1 = v1;
}

// ---------------- weight prep: w_fc0 [48][128] -> w0T [128][48] ----------------
__global__ __launch_bounds__(256) void k_prep_weights(const float* __restrict__ wfc0,
                                                      float* __restrict__ w0T) {
  const int i = blockIdx.x * 256 + threadIdx.x;  // over 6144
  if (i < HIDD * 48) {
    const int d = i / 48;
    const int c = i - d * 48;
    w0T[i] = wfc0[c * HIDD + d];
  }
}

// ---------------- NCHW -> NHWC state init ----------------
__global__ __launch_bounds__(256) void k_nchw_to_nhwc(const float* __restrict__ x,
                                                      float* __restrict__ st) {
  const int p = blockIdx.x * 256 + threadIdx.x;
  const int b = p >> 16;
  const int hw = p & 65535;
  const float* src = x + (size_t)b * (Cc * HW) + hw;
  float v[16];
#pragma unroll
  for (int c = 0; c < 16; c++) v[c] = src[(size_t)c * HW];
  float4* dst = (float4*)(st + (size_t)p * 16);
#pragma unroll
  for (int q = 0; q < 4; q++)
    dst[q] = make_float4(v[4 * q], v[4 * q + 1], v[4 * q + 2], v[4 * q + 3]);
}

// ---------------- One NCA step ----------------
// Weights are wave-uniform -> read via uniform indices from global so the
// compiler emits s_load into SGPRs (scalar pipe dual-issues with VALU;
// v_fmac can take 1 SGPR operand). No LDS at all.
__global__ __launch_bounds__(256) void k_step(const float* __restrict__ in,
                                              float* __restrict__ out,
                                              const float* __restrict__ wp0,
                                              const float* __restrict__ wp1,
                                              const float* __restrict__ w0T,
                                              const float* __restrict__ bfc0,
                                              const float* __restrict__ wfc1,
                                              uint32_t key0, uint32_t key1) {
  const int tid = threadIdx.x;
  const int b = blockIdx.x >> 8;
  const int h = blockIdx.x & 255;
  const int w = tid;
  // 'reflect' padding: -1 -> 1, H -> H-2
  const int rows[3] = { (h == 0) ? 1 : h - 1, h, (h == 255) ? 254 : h + 1 };
  const int cols[3] = { (w == 0) ? 1 : w - 1, w, (w == 255) ? 254 : w + 1 };

  float perc[48];
#pragma unroll
  for (int i = 16; i < 48; i++) perc[i] = 0.f;

#pragma unroll
  for (int ty = 0; ty < 3; ty++) {
#pragma unroll
    for (int tx = 0; tx < 3; tx++) {
      const int tap = ty * 3 + tx;
      const float4* pv =
          (const float4*)(in + (size_t)(((b << 8) + rows[ty]) * 256 + cols[tx]) * 16);
#pragma unroll
      for (int q = 0; q < 4; q++) {
        float4 v = pv[q];
        float vv[4] = { v.x, v.y, v.z, v.w };
#pragma unroll
        for (int j = 0; j < 4; j++) {
          const int c = 4 * q + j;
          perc[16 + c] = fmaf(wp0[tap * 16 + c], vv[j], perc[16 + c]);
          perc[32 + c] = fmaf(wp1[tap * 16 + c], vv[j], perc[32 + c]);
          if (tap == 4) perc[c] = vv[j];
        }
      }
    }
  }

  // Only channels 3..15 of dx are ever used (ch 0-2 are clamped to img).
  float dx[13];
#pragma unroll
  for (int c = 0; c < 13; c++) dx[c] = 0.f;

#pragma unroll 2
  for (int d = 0; d < HIDD; d++) {
    float hd = bfc0[d];
    const float* wr = &w0T[d * 48];
#pragma unroll
    for (int c = 0; c < 48; c++) hd = fmaf(perc[c], wr[c], hd);
    hd = fmaxf(hd, 0.f);
    const float* w1r = &wfc1[d * 16];
#pragma unroll
    for (int c = 0; c < 13; c++) dx[c] = fmaf(hd, w1r[c + 3], dx[c]);
  }

  // JAX partitionable threefry uniform: bits = out0 ^ out1 of
  // threefry(step_key, (hi=0, lo=linear_pixel_index))
  const uint32_t p = (uint32_t)((blockIdx.x << 8) + w);
  uint32_t o0, o1;
  threefry2x32(key0, key1, 0u, p, o0, o1);
  const uint32_t bits = o0 ^ o1;
  const float u = __uint_as_float((bits >> 9) | 0x3f800000u) - 1.0f;
  const float mask = (u <= 0.5f) ? 1.0f : 0.0f;

  float o[16];
#pragma unroll
  for (int c = 0; c < 16; c++)
    o[c] = (c < 3) ? perc[c] : fmaf(mask, dx[c - 3], perc[c]);
  float4* dst = (float4*)(out + (size_t)p * 16);
#pragma unroll
  for (int q = 0; q < 4; q++)
    dst[q] = make_float4(o[4 * q], o[4 * q + 1], o[4 * q + 2], o[4 * q + 3]);
}

// ---------------- NHWC state -> (out slice, x_final NCHW) ----------------
__global__ __launch_bounds__(256) void k_nhwc_to_out(const float* __restrict__ st,
                                                     float* __restrict__ outp) {
  const int p = blockIdx.x * 256 + threadIdx.x;
  const int b = p >> 16;
  const int hw = p & 65535;
  const float4* src = (const float4*)(st + (size_t)p * 16);
  float v[16];
#pragma unroll
  for (int q = 0; q < 4; q++) {
    float4 t = src[q];
    v[4 * q] = t.x; v[4 * q + 1] = t.y; v[4 * q + 2] = t.z; v[4 * q + 3] = t.w;
  }
  float* xf = outp + NPIX;  // x_final region of d_out
#pragma unroll
  for (int c = 0; c < 16; c++) xf[(size_t)(b * 16 + c) * HW + hw] = v[c];
  outp[(size_t)b * HW + hw] = v[3];  // out = x_final[:, 3:4]
}

extern "C" void kernel_launch(void* const* d_in, const int* in_sizes, int n_in,
                              void* d_out, int out_size, void* d_ws, size_t ws_size,
                              hipStream_t stream) {
  const float* x    = (const float*)d_in[0];
  const float* wp0  = (const float*)d_in[1];
  const float* wp1  = (const float*)d_in[2];
  const float* wfc0 = (const float*)d_in[3];
  const float* bfc0 = (const float*)d_in[4];
  const float* wfc1 = (const float*)d_in[5];
  float* out = (float*)d_out;

  float* w0T = (float*)d_ws;          // 6144 floats (24 KB), transposed w_fc0
  float* S0  = (float*)d_ws + 8192;   // 33.5 MB scratch state
  float* S1  = out + NPIX;            // x_final region doubles as scratch

  // Step keys: foldlike split of key(42): keys[s] = threefry((0,42),(0,s))
  uint32_t k0[NSTEPS], k1[NSTEPS];
  for (int s = 0; s < NSTEPS; s++)
    threefry2x32(0u, 42u, 0u, (uint32_t)s, k0[s], k1[s]);

  dim3 grid(Bn * Hh), block(256);
  hipLaunchKernelGGL(k_prep_weights, dim3(24), block, 0, stream, wfc0, w0T);
  hipLaunchKernelGGL(k_nchw_to_nhwc, grid, block, 0, stream, x, S0);
  float* cur = S0;
  float* nxt = S1;
  for (int s = 0; s < NSTEPS; s++) {
    hipLaunchKernelGGL(k_step, grid, block, 0, stream,
                       cur, nxt, wp0, wp1, w0T, bfc0, wfc1, k0[s], k1[s]);
    float* t = cur; cur = nxt; nxt = t;
  }
  // 32 steps (even) -> final state back in S0
  hipLaunchKernelGGL(k_nhwc_to_out, grid, block, 0, stream, cur, out);
}

// Round 3
// 4306.678 us; speedup vs baseline: 1.5376x; 1.0017x over previous
//
#include <hip/hip_runtime.h>
#include <stdint.h>

#define Cc   16
#define HIDD 128
#define Bn   8
#define Hh   256
#define Ww   256
#define HW   (Hh * Ww)         // 65536
#define NPIX (Bn * HW)         // 524288
#define NSTEPS 32
#define CHUNK 512              // pixels per block (2 rows)

// ---------------- JAX threefry2x32 (20 rounds), host+device ----------------
__host__ __device__ inline void threefry2x32(uint32_t k1, uint32_t k2,
                                             uint32_t x0, uint32_t x1,
                                             uint32_t& o0, uint32_t& o1) {
  const uint32_t ks2 = k1 ^ k2 ^ 0x1BD11BDAu;
  uint32_t v0 = x0 + k1;
  uint32_t v1 = x1 + k2;
#define ROTL32(x, n) (((x) << (n)) | ((x) >> (32 - (n))))
#define R4(a, b, c, d)                                    \
  { v0 += v1; v1 = ROTL32(v1, a); v1 ^= v0;               \
    v0 += v1; v1 = ROTL32(v1, b); v1 ^= v0;               \
    v0 += v1; v1 = ROTL32(v1, c); v1 ^= v0;               \
    v0 += v1; v1 = ROTL32(v1, d); v1 ^= v0; }
  R4(13, 15, 26, 6)   v0 += k2;  v1 += ks2 + 1u;
  R4(17, 29, 16, 24)  v0 += ks2; v1 += k1 + 2u;
  R4(13, 15, 26, 6)   v0 += k1;  v1 += k2 + 3u;
  R4(17, 29, 16, 24)  v0 += k2;  v1 += ks2 + 4u;
  R4(13, 15, 26, 6)   v0 += ks2; v1 += k1 + 5u;
#undef R4
#undef ROTL32
  o0 = v0;
  o1 = v1;
}

__device__ inline bool fire_mask(uint32_t key0, uint32_t key1, uint32_t p) {
  uint32_t o0, o1;
  threefry2x32(key0, key1, 0u, p, o0, o1);
  const uint32_t bits = o0 ^ o1;
  const float u = __uint_as_float((bits >> 9) | 0x3f800000u) - 1.0f;
  return u <= 0.5f;
}

// ---- weight prep: w0T[128][48] = w_fc0^T ; w1p[128][16] = w_fc1[:,3:16] packed ----
__global__ __launch_bounds__(256) void k_prep_weights(const float* __restrict__ wfc0,
                                                      const float* __restrict__ wfc1,
                                                      float* __restrict__ w0T,
                                                      float* __restrict__ w1p) {
  const int i = blockIdx.x * 256 + threadIdx.x;  // over 8192
  if (i < HIDD * 48) {
    const int d = i / 48;
    const int c = i - d * 48;
    w0T[i] = wfc0[c * HIDD + d];
  } else if (i < HIDD * 48 + HIDD * 16) {
    const int j16 = i - HIDD * 48;
    const int d = j16 >> 4;
    const int j = j16 & 15;
    w1p[j16] = (j < 13) ? wfc1[d * 16 + 3 + j] : 0.f;
  }
}

// ---------------- NCHW -> NHWC state init ----------------
__global__ __launch_bounds__(256) void k_nchw_to_nhwc(const float* __restrict__ x,
                                                      float* __restrict__ st) {
  const int p = blockIdx.x * 256 + threadIdx.x;
  const int b = p >> 16;
  const int hw = p & 65535;
  const float* src = x + (size_t)b * (Cc * HW) + hw;
  float v[16];
#pragma unroll
  for (int c = 0; c < 16; c++) v[c] = src[(size_t)c * HW];
  float4* dst = (float4*)(st + (size_t)p * 16);
#pragma unroll
  for (int q = 0; q < 4; q++)
    dst[q] = make_float4(v[4 * q], v[4 * q + 1], v[4 * q + 2], v[4 * q + 3]);
}

// ---------------- One NCA step (active-pixel compaction) ----------------
// Fire mask depends only on (step key, pixel index) -> ~50% of pixels are
// bitwise copies. Compact active ids into LDS via wave ballots; run the MLP
// only on actives. Weights stream through SGPRs (uniform addresses).
__global__ __launch_bounds__(256, 1) void k_step(const float* __restrict__ in,
                                                 float* __restrict__ out,
                                                 const float* __restrict__ wp0,
                                                 const float* __restrict__ wp1,
                                                 const float* __restrict__ w0T,
                                                 const float* __restrict__ bfc0,
                                                 const float* __restrict__ w1p,
                                                 uint32_t key0, uint32_t key1) {
  __shared__ uint32_t s_list[CHUNK];
  __shared__ int s_cnt;

  const int tid = threadIdx.x;
  const uint32_t base = blockIdx.x * CHUNK;
  if (tid == 0) s_cnt = 0;
  __syncthreads();

  // ---- phase 1: masks + wave-ballot compaction ----
  bool act[2];
  uint32_t pp[2];
#pragma unroll
  for (int k = 0; k < 2; k++) {
    pp[k] = base + (uint32_t)(k * 256 + tid);
    act[k] = fire_mask(key0, key1, pp[k]);
  }
  const int lid = __lane_id();
#pragma unroll
  for (int k = 0; k < 2; k++) {
    const unsigned long long bal = __ballot(act[k]);
    const int pos = __popcll(bal & ((1ULL << lid) - 1ULL));
    const int tot = __popcll(bal);
    int bs = 0;
    if (lid == 0) bs = atomicAdd(&s_cnt, tot);
    bs = __shfl(bs, 0);
    if (act[k]) s_list[bs + pos] = pp[k];
  }
  __syncthreads();
  const int n = s_cnt;

  // ---- phase 2: copy inactive pixels (bitwise identity update) ----
#pragma unroll
  for (int k = 0; k < 2; k++) {
    if (!act[k]) {
      const float4* s = (const float4*)(in + (size_t)pp[k] * 16);
      float4* d = (float4*)(out + (size_t)pp[k] * 16);
#pragma unroll
      for (int q = 0; q < 4; q++) d[q] = s[q];
    }
  }

  // ---- phase 3: MLP for active pixels ----
  for (int i = tid; i < n; i += 256) {
    const uint32_t p = s_list[i];
    const int b = p >> 16;
    const int hw = p & 65535;
    const int h = hw >> 8;
    const int w = hw & 255;
    const int rows[3] = { (h == 0) ? 1 : h - 1, h, (h == 255) ? 254 : h + 1 };
    const int cols[3] = { (w == 0) ? 1 : w - 1, w, (w == 255) ? 254 : w + 1 };

    float perc[48];
#pragma unroll
    for (int c = 16; c < 48; c++) perc[c] = 0.f;

#pragma unroll
    for (int ty = 0; ty < 3; ty++) {
#pragma unroll
      for (int tx = 0; tx < 3; tx++) {
        const int tap = ty * 3 + tx;
        const float4* pv =
            (const float4*)(in + (size_t)(((b << 8) + rows[ty]) * 256 + cols[tx]) * 16);
#pragma unroll
        for (int q = 0; q < 4; q++) {
          float4 v = pv[q];
          float vv[4] = { v.x, v.y, v.z, v.w };
#pragma unroll
          for (int j = 0; j < 4; j++) {
            const int c = 4 * q + j;
            perc[16 + c] = fmaf(wp0[tap * 16 + c], vv[j], perc[16 + c]);
            perc[32 + c] = fmaf(wp1[tap * 16 + c], vv[j], perc[32 + c]);
            if (tap == 4) perc[c] = vv[j];
          }
        }
      }
    }

    float dx[13];
#pragma unroll
    for (int c = 0; c < 13; c++) dx[c] = 0.f;

#pragma unroll 2
    for (int d = 0; d < HIDD; d++) {
      float hd = bfc0[d];
      const float* wr = &w0T[d * 48];
#pragma unroll
      for (int c = 0; c < 48; c++) hd = fmaf(perc[c], wr[c], hd);
      hd = fmaxf(hd, 0.f);
      const float* w1r = &w1p[d * 16];
#pragma unroll
      for (int c = 0; c < 13; c++) dx[c] = fmaf(hd, w1r[c], dx[c]);
    }

    float o[16];
#pragma unroll
    for (int c = 0; c < 16; c++)
      o[c] = (c < 3) ? perc[c] : (perc[c] + dx[c - 3]);
    float4* dst = (float4*)(out + (size_t)p * 16);
#pragma unroll
    for (int q = 0; q < 4; q++)
      dst[q] = make_float4(o[4 * q], o[4 * q + 1], o[4 * q + 2], o[4 * q + 3]);
  }
}

// ---------------- NHWC state -> (out slice, x_final NCHW) ----------------
__global__ __launch_bounds__(256) void k_nhwc_to_out(const float* __restrict__ st,
                                                     float* __restrict__ outp) {
  const int p = blockIdx.x * 256 + threadIdx.x;
  const int b = p >> 16;
  const int hw = p & 65535;
  const float4* src = (const float4*)(st + (size_t)p * 16);
  float v[16];
#pragma unroll
  for (int q = 0; q < 4; q++) {
    float4 t = src[q];
    v[4 * q] = t.x; v[4 * q + 1] = t.y; v[4 * q + 2] = t.z; v[4 * q + 3] = t.w;
  }
  float* xf = outp + NPIX;  // x_final region of d_out
#pragma unroll
  for (int c = 0; c < 16; c++) xf[(size_t)(b * 16 + c) * HW + hw] = v[c];
  outp[(size_t)b * HW + hw] = v[3];  // out = x_final[:, 3:4]
}

extern "C" void kernel_launch(void* const* d_in, const int* in_sizes, int n_in,
                              void* d_out, int out_size, void* d_ws, size_t ws_size,
                              hipStream_t stream) {
  const float* x    = (const float*)d_in[0];
  const float* wp0  = (const float*)d_in[1];
  const float* wp1  = (const float*)d_in[2];
  const float* wfc0 = (const float*)d_in[3];
  const float* bfc0 = (const float*)d_in[4];
  const float* wfc1 = (const float*)d_in[5];
  float* out = (float*)d_out;

  float* w0T = (float*)d_ws;          // 6144 floats
  float* w1p = (float*)d_ws + 6144;   // 2048 floats
  float* S0  = (float*)d_ws + 8192;   // 33.5 MB scratch state
  float* S1  = out + NPIX;            // x_final region doubles as scratch

  // Step keys: foldlike split of key(42): keys[s] = threefry((0,42),(0,s))
  uint32_t k0[NSTEPS], k1[NSTEPS];
  for (int s = 0; s < NSTEPS; s++)
    threefry2x32(0u, 42u, 0u, (uint32_t)s, k0[s], k1[s]);

  dim3 block(256);
  hipLaunchKernelGGL(k_prep_weights, dim3(32), block, 0, stream, wfc0, wfc1, w0T, w1p);
  hipLaunchKernelGGL(k_nchw_to_nhwc, dim3(NPIX / 256), block, 0, stream, x, S0);
  float* cur = S0;
  float* nxt = S1;
  for (int s = 0; s < NSTEPS; s++) {
    hipLaunchKernelGGL(k_step, dim3(NPIX / CHUNK), block, 0, stream,
                       cur, nxt, wp0, wp1, w0T, bfc0, w1p, k0[s], k1[s]);
    float* t = cur; cur = nxt; nxt = t;
  }
  // 32 steps (even) -> final state back in S0
  hipLaunchKernelGGL(k_nhwc_to_out, dim3(NPIX / 256), block, 0, stream, cur, out);
}

// Round 4
// 1903.361 us; speedup vs baseline: 3.4790x; 2.2627x over previous
//
#include <hip/hip_runtime.h>
#include <stdint.h>

#define Cc   16
#define HIDD 128
#define Bn   8
#define Hh   256
#define Ww   256
#define HW   (Hh * Ww)         // 65536
#define NPIX (Bn * HW)         // 524288
#define NSTEPS 32

typedef _Float16 half8 __attribute__((ext_vector_type(8)));
typedef float floatx16 __attribute__((ext_vector_type(16)));

// ---------------- JAX threefry2x32 (20 rounds), host+device ----------------
__host__ __device__ inline void threefry2x32(uint32_t k1, uint32_t k2,
                                             uint32_t x0, uint32_t x1,
                                             uint32_t& o0, uint32_t& o1) {
  const uint32_t ks2 = k1 ^ k2 ^ 0x1BD11BDAu;
  uint32_t v0 = x0 + k1;
  uint32_t v1 = x1 + k2;
#define ROTL32(x, n) (((x) << (n)) | ((x) >> (32 - (n))))
#define R4(a, b, c, d)                                    \
  { v0 += v1; v1 = ROTL32(v1, a); v1 ^= v0;               \
    v0 += v1; v1 = ROTL32(v1, b); v1 ^= v0;               \
    v0 += v1; v1 = ROTL32(v1, c); v1 ^= v0;               \
    v0 += v1; v1 = ROTL32(v1, d); v1 ^= v0; }
  R4(13, 15, 26, 6)   v0 += k2;  v1 += ks2 + 1u;
  R4(17, 29, 16, 24)  v0 += ks2; v1 += k1 + 2u;
  R4(13, 15, 26, 6)   v0 += k1;  v1 += k2 + 3u;
  R4(17, 29, 16, 24)  v0 += k2;  v1 += ks2 + 4u;
  R4(13, 15, 26, 6)   v0 += ks2; v1 += k1 + 5u;
#undef R4
#undef ROTL32
  o0 = v0;
  o1 = v1;
}

__device__ inline uint32_t pk2(_Float16 a, _Float16 b) {
  union { _Float16 h[2]; uint32_t u; } t;
  t.h[0] = a; t.h[1] = b;
  return t.u;
}
__device__ inline half8 mk8(uint32_t a, uint32_t b, uint32_t c, uint32_t d) {
  union { uint32_t u[4]; half8 h; } t;
  t.u[0] = a; t.u[1] = b; t.u[2] = c; t.u[3] = d;
  return t.h;
}

// ---- prep: pack W0^T / W1p^T into 32x32x16 A-fragment order (f16 hi/lo) ----
// w0frag: [Mt(4)][kt(3)][spl(2)][lane(64)][j(8)]  value = split(W0[k][m]),
//   m = Mt*32+(lane&31), k = kt*16 + (lane>>5)*8 + j
// w1frag (offset 12288): [kt2(8)][spl(2)][lane][j] value = split(W1pT[m][k]),
//   m = lane&31 (dx ch, valid<13), k = kt2*16 + (lane>>5)*8 + j
__global__ __launch_bounds__(256) void k_prep(const float* __restrict__ wfc0,
                                              const float* __restrict__ wfc1,
                                              unsigned short* __restrict__ wf) {
  const int idx = blockIdx.x * 256 + threadIdx.x;
  if (idx < 12288) {
    const int j = idx & 7;
    const int t = idx >> 3;
    const int lane = t & 63;
    const int t2 = t >> 6;
    const int spl = t2 & 1;
    const int fk = t2 >> 1;
    const int kt = fk % 3;
    const int Mt = fk / 3;
    const int m = Mt * 32 + (lane & 31);
    const int k = kt * 16 + (lane >> 5) * 8 + j;
    const float v = wfc0[k * HIDD + m];
    const _Float16 hi = (_Float16)v;
    const _Float16 r = spl ? (_Float16)(v - (float)hi) : hi;
    union { _Float16 h; unsigned short s; } cv; cv.h = r;
    wf[idx] = cv.s;
  } else if (idx < 20480) {
    const int idx2 = idx - 12288;
    const int j = idx2 & 7;
    const int t = idx2 >> 3;
    const int lane = t & 63;
    const int t2 = t >> 6;
    const int spl = t2 & 1;
    const int kt2 = t2 >> 1;
    const int m = lane & 31;
    const int k = kt2 * 16 + (lane >> 5) * 8 + j;
    const float v = (m < 13) ? wfc1[k * 16 + (m + 3)] : 0.f;
    const _Float16 hi = (_Float16)v;
    const _Float16 r = spl ? (_Float16)(v - (float)hi) : hi;
    union { _Float16 h; unsigned short s; } cv; cv.h = r;
    wf[idx] = cv.s;
  }
}

// ---------------- NCHW -> NHWC state init ----------------
__global__ __launch_bounds__(256) void k_nchw_to_nhwc(const float* __restrict__ x,
                                                      float* __restrict__ st) {
  const int p = blockIdx.x * 256 + threadIdx.x;
  const int b = p >> 16;
  const int hw = p & 65535;
  const float* src = x + (size_t)b * (Cc * HW) + hw;
  float v[16];
#pragma unroll
  for (int c = 0; c < 16; c++) v[c] = src[(size_t)c * HW];
  float4* dst = (float4*)(st + (size_t)p * 16);
#pragma unroll
  for (int q = 0; q < 4; q++)
    dst[q] = make_float4(v[4 * q], v[4 * q + 1], v[4 * q + 2], v[4 * q + 3]);
}

// ---------------- One NCA step: perception (VALU) + MLP (MFMA) ----------------
__global__ __launch_bounds__(256) void k_step(const float* __restrict__ in,
                                              float* __restrict__ out,
                                              const float* __restrict__ wp0,
                                              const float* __restrict__ wp1,
                                              const unsigned short* __restrict__ wf,
                                              const float* __restrict__ bfc0,
                                              uint32_t key0, uint32_t key1) {
  __shared__ __align__(16) unsigned short s_wf[20480];  // 40960 B
  __shared__ __align__(16) float s_bias[128];

  const int tid = threadIdx.x;
  {
    const uint4* src = (const uint4*)wf;
    uint4* dst = (uint4*)s_wf;
#pragma unroll
    for (int i = 0; i < 10; i++) dst[tid + 256 * i] = src[tid + 256 * i];
    if (tid < 32) ((float4*)s_bias)[tid] = ((const float4*)bfc0)[tid];
  }
  __syncthreads();

  const int lane = tid & 63;
  const int h8 = (tid >> 5) & 1;
  const int ln31 = tid & 31;
  const int wv = tid >> 6;
  const uint32_t wbase = ((uint32_t)blockIdx.x << 8) + (uint32_t)wv * 64u;

  // ---- perception: pixel p = row-base + tid ----
  const int b = blockIdx.x >> 8;
  const int h = blockIdx.x & 255;
  const int w = tid;
  const int rows[3] = { (h == 0) ? 1 : h - 1, h, (h == 255) ? 254 : h + 1 };
  const int cols[3] = { (w == 0) ? 1 : w - 1, w, (w == 255) ? 254 : w + 1 };

  float perc[48];
#pragma unroll
  for (int i = 16; i < 48; i++) perc[i] = 0.f;

#pragma unroll
  for (int ty = 0; ty < 3; ty++) {
#pragma unroll
    for (int tx = 0; tx < 3; tx++) {
      const int tap = ty * 3 + tx;
      const float4* pv =
          (const float4*)(in + (size_t)(((b << 8) + rows[ty]) * 256 + cols[tx]) * 16);
#pragma unroll
      for (int q = 0; q < 4; q++) {
        float4 v = pv[q];
        float vv[4] = { v.x, v.y, v.z, v.w };
#pragma unroll
        for (int j = 0; j < 4; j++) {
          const int c = 4 * q + j;
          perc[16 + c] = fmaf(wp0[tap * 16 + c], vv[j], perc[16 + c]);
          perc[32 + c] = fmaf(wp1[tap * 16 + c], vv[j], perc[32 + c]);
          if (tap == 4) perc[c] = vv[j];
        }
      }
    }
  }

  // ---- split perc to f16 hi/lo, packed as dword pairs (k even in low half) ----
  uint32_t hi2[24], lo2[24];
#pragma unroll
  for (int q = 0; q < 24; q++) {
    const float a = perc[2 * q], bq = perc[2 * q + 1];
    const _Float16 ah = (_Float16)a, bh = (_Float16)bq;
    const _Float16 al = (_Float16)(a - (float)ah), bl = (_Float16)(bq - (float)bh);
    hi2[q] = pk2(ah, bh);
    lo2[q] = pk2(al, bl);
  }

  // ---- GEMM1 B-fragments (P^T): n=lane&31=pixel, k-slot = 8*h8 + j ----
  // nt0 pixels wbase+0..31, nt1 pixels wbase+32..63 (partner = lane^32)
  uint32_t B0h[3][4], B0l[3][4], B1h[3][4], B1l[3][4];
#pragma unroll
  for (int kt = 0; kt < 3; kt++) {
#pragma unroll
    for (int d = 0; d < 4; d++) {
      const uint32_t olh = hi2[kt * 8 + d], ohh = hi2[kt * 8 + 4 + d];
      const uint32_t pl_h = __shfl_xor(olh, 32, 64);
      const uint32_t ph_h = __shfl_xor(ohh, 32, 64);
      B0h[kt][d] = h8 ? ph_h : olh;
      B1h[kt][d] = h8 ? ohh : pl_h;
      const uint32_t oll = lo2[kt * 8 + d], ohl = lo2[kt * 8 + 4 + d];
      const uint32_t pl_l = __shfl_xor(oll, 32, 64);
      const uint32_t ph_l = __shfl_xor(ohl, 32, 64);
      B0l[kt][d] = h8 ? ph_l : oll;
      B1l[kt][d] = h8 ? ohl : pl_l;
    }
  }

  floatx16 g2a, g2b;
#pragma unroll
  for (int i = 0; i < 16; i++) { g2a[i] = 0.f; g2b[i] = 0.f; }

#pragma unroll
  for (int Mt = 0; Mt < 4; Mt++) {
    // A-fragments of W0^T (hi/lo) from LDS, conflict-free b128
    half8 Ah[3], Al[3];
#pragma unroll
    for (int kt = 0; kt < 3; kt++) {
      Ah[kt] = *(const half8*)&s_wf[((Mt * 3 + kt) * 2 + 0) * 512 + lane * 8];
      Al[kt] = *(const half8*)&s_wf[((Mt * 3 + kt) * 2 + 1) * 512 + lane * 8];
    }
    // bias init per D-row: row = (r&3) + 8*(r>>2) + 4*h8
    const float4 bb0 = *(const float4*)&s_bias[Mt * 32 + 4 * h8];
    const float4 bb1 = *(const float4*)&s_bias[Mt * 32 + 8 + 4 * h8];
    const float4 bb2 = *(const float4*)&s_bias[Mt * 32 + 16 + 4 * h8];
    const float4 bb3 = *(const float4*)&s_bias[Mt * 32 + 24 + 4 * h8];
    floatx16 acc0 = { bb0.x, bb0.y, bb0.z, bb0.w, bb1.x, bb1.y, bb1.z, bb1.w,
                      bb2.x, bb2.y, bb2.z, bb2.w, bb3.x, bb3.y, bb3.z, bb3.w };
    floatx16 acc1 = acc0;

#pragma unroll
    for (int kt = 0; kt < 3; kt++) {
      const half8 b0h = mk8(B0h[kt][0], B0h[kt][1], B0h[kt][2], B0h[kt][3]);
      const half8 b0l = mk8(B0l[kt][0], B0l[kt][1], B0l[kt][2], B0l[kt][3]);
      const half8 b1h = mk8(B1h[kt][0], B1h[kt][1], B1h[kt][2], B1h[kt][3]);
      const half8 b1l = mk8(B1l[kt][0], B1l[kt][1], B1l[kt][2], B1l[kt][3]);
      acc0 = __builtin_amdgcn_mfma_f32_32x32x16_f16(Ah[kt], b0h, acc0, 0, 0, 0);
      acc0 = __builtin_amdgcn_mfma_f32_32x32x16_f16(Al[kt], b0h, acc0, 0, 0, 0);
      acc0 = __builtin_amdgcn_mfma_f32_32x32x16_f16(Ah[kt], b0l, acc0, 0, 0, 0);
      acc1 = __builtin_amdgcn_mfma_f32_32x32x16_f16(Ah[kt], b1h, acc1, 0, 0, 0);
      acc1 = __builtin_amdgcn_mfma_f32_32x32x16_f16(Al[kt], b1h, acc1, 0, 0, 0);
      acc1 = __builtin_amdgcn_mfma_f32_32x32x16_f16(Ah[kt], b1l, acc1, 0, 0, 0);
    }

    // ---- H-transform + GEMM2 accumulate: kt2 = 2*Mt+u covers hid rows of Mt ----
#pragma unroll
    for (int u = 0; u < 2; u++) {
      const int kt2 = 2 * Mt + u;
      const half8 W1h = *(const half8*)&s_wf[12288 + (kt2 * 2 + 0) * 512 + lane * 8];
      const half8 W1l = *(const half8*)&s_wf[12288 + (kt2 * 2 + 1) * 512 + lane * 8];
#pragma unroll
      for (int nt = 0; nt < 2; nt++) {
        float hv[8];
#pragma unroll
        for (int s = 0; s < 8; s++) {
          const float v = nt ? acc1[8 * u + s] : acc0[8 * u + s];
          hv[s] = fmaxf(v, 0.f);
        }
        uint32_t pkh[4], pkl[4];
#pragma unroll
        for (int d = 0; d < 4; d++) {
          const float a = hv[2 * d], bq = hv[2 * d + 1];
          const _Float16 ah = (_Float16)a, bh = (_Float16)bq;
          const _Float16 al = (_Float16)(a - (float)ah), bl = (_Float16)(bq - (float)bh);
          pkh[d] = pk2(ah, bh);
          pkl[d] = pk2(al, bl);
        }
        uint32_t shh[4], shl[4];
#pragma unroll
        for (int d = 0; d < 4; d++) {
          shh[d] = __shfl_xor(pkh[d], 32, 64);
          shl[d] = __shfl_xor(pkl[d], 32, 64);
        }
        // frag dwords: d0d1 = half0-source quad(2u+h8); d2d3 = half1-source quad(2u+h8)
        const half8 Bh2 = mk8(h8 ? shh[2] : pkh[0], h8 ? shh[3] : pkh[1],
                              h8 ? pkh[2] : shh[0], h8 ? pkh[3] : shh[1]);
        const half8 Bl2 = mk8(h8 ? shl[2] : pkl[0], h8 ? shl[3] : pkl[1],
                              h8 ? pkl[2] : shl[0], h8 ? pkl[3] : shl[1]);
        if (nt == 0) {
          g2a = __builtin_amdgcn_mfma_f32_32x32x16_f16(W1h, Bh2, g2a, 0, 0, 0);
          g2a = __builtin_amdgcn_mfma_f32_32x32x16_f16(W1l, Bh2, g2a, 0, 0, 0);
          g2a = __builtin_amdgcn_mfma_f32_32x32x16_f16(W1h, Bl2, g2a, 0, 0, 0);
        } else {
          g2b = __builtin_amdgcn_mfma_f32_32x32x16_f16(W1h, Bh2, g2b, 0, 0, 0);
          g2b = __builtin_amdgcn_mfma_f32_32x32x16_f16(W1l, Bh2, g2b, 0, 0, 0);
          g2b = __builtin_amdgcn_mfma_f32_32x32x16_f16(W1h, Bl2, g2b, 0, 0, 0);
        }
      }
    }
  }

  // ---- epilogue: dx^T rows m=(r&3)+8*(r>>2)+4*h8 (valid regs 0..7), col=pixel ----
#pragma unroll
  for (int nt = 0; nt < 2; nt++) {
    float dxv[8], odx[8];
#pragma unroll
    for (int i = 0; i < 8; i++) dxv[i] = nt ? g2b[i] : g2a[i];
#pragma unroll
    for (int i = 0; i < 8; i++) odx[i] = __shfl_xor(dxv[i], 32, 64);
    const uint32_t p = wbase + (uint32_t)(nt * 32) + (uint32_t)ln31;
    uint32_t t0, t1;
    threefry2x32(key0, key1, 0u, p, t0, t1);
    const uint32_t bits = t0 ^ t1;
    const float uu = __uint_as_float((bits >> 9) | 0x3f800000u) - 1.0f;
    const float M = (uu <= 0.5f) ? 1.f : 0.f;
    const float4* sp = (const float4*)(in + (size_t)p * 16);
    const float4 sA = sp[2 * h8];
    const float4 sB = sp[2 * h8 + 1];
    float4 oA, oB;
    // h8=0 owns ch0..7 (dx m0..3 = r0..3, m4 from partner r0)
    // h8=1 owns ch8..15 (m5..7 = r1..3, m8..11 = partner r4..7, m12 = r4)
    oA.x = h8 ? fmaf(M, dxv[1], sA.x) : sA.x;
    oA.y = h8 ? fmaf(M, dxv[2], sA.y) : sA.y;
    oA.z = h8 ? fmaf(M, dxv[3], sA.z) : sA.z;
    oA.w = fmaf(M, h8 ? odx[4] : dxv[0], sA.w);
    oB.x = fmaf(M, h8 ? odx[5] : dxv[1], sB.x);
    oB.y = fmaf(M, h8 ? odx[6] : dxv[2], sB.y);
    oB.z = fmaf(M, h8 ? odx[7] : dxv[3], sB.z);
    oB.w = fmaf(M, h8 ? dxv[4] : odx[0], sB.w);
    float4* dp = (float4*)(out + (size_t)p * 16);
    dp[2 * h8] = oA;
    dp[2 * h8 + 1] = oB;
  }
}

// ---------------- NHWC state -> (out slice, x_final NCHW) ----------------
__global__ __launch_bounds__(256) void k_nhwc_to_out(const float* __restrict__ st,
                                                     float* __restrict__ outp) {
  const int p = blockIdx.x * 256 + threadIdx.x;
  const int b = p >> 16;
  const int hw = p & 65535;
  const float4* src = (const float4*)(st + (size_t)p * 16);
  float v[16];
#pragma unroll
  for (int q = 0; q < 4; q++) {
    float4 t = src[q];
    v[4 * q] = t.x; v[4 * q + 1] = t.y; v[4 * q + 2] = t.z; v[4 * q + 3] = t.w;
  }
  float* xf = outp + NPIX;  // x_final region of d_out
#pragma unroll
  for (int c = 0; c < 16; c++) xf[(size_t)(b * 16 + c) * HW + hw] = v[c];
  outp[(size_t)b * HW + hw] = v[3];  // out = x_final[:, 3:4]
}

extern "C" void kernel_launch(void* const* d_in, const int* in_sizes, int n_in,
                              void* d_out, int out_size, void* d_ws, size_t ws_size,
                              hipStream_t stream) {
  const float* x    = (const float*)d_in[0];
  const float* wp0  = (const float*)d_in[1];
  const float* wp1  = (const float*)d_in[2];
  const float* wfc0 = (const float*)d_in[3];
  const float* bfc0 = (const float*)d_in[4];
  const float* wfc1 = (const float*)d_in[5];
  float* out = (float*)d_out;

  unsigned short* wf = (unsigned short*)d_ws;          // 20480 f16 (40960 B)
  float* S0 = (float*)((char*)d_ws + 65536);           // 33.5 MB scratch state
  float* S1 = out + NPIX;                              // x_final region as scratch

  // Step keys: foldlike split of key(42): keys[s] = threefry((0,42),(0,s))
  uint32_t k0[NSTEPS], k1[NSTEPS];
  for (int s = 0; s < NSTEPS; s++)
    threefry2x32(0u, 42u, 0u, (uint32_t)s, k0[s], k1[s]);

  dim3 block(256);
  hipLaunchKernelGGL(k_prep, dim3(80), block, 0, stream, wfc0, wfc1, wf);
  hipLaunchKernelGGL(k_nchw_to_nhwc, dim3(NPIX / 256), block, 0, stream, x, S0);
  float* cur = S0;
  float* nxt = S1;
  for (int s = 0; s < NSTEPS; s++) {
    hipLaunchKernelGGL(k_step, dim3(Bn * Hh), block, 0, stream,
                       cur, nxt, wp0, wp1, wf, bfc0, k0[s], k1[s]);
    float* t = cur; cur = nxt; nxt = t;
  }
  // 32 steps (even) -> final state back in S0
  hipLaunchKernelGGL(k_nhwc_to_out, dim3(NPIX / 256), block, 0, stream, cur, out);
}